// Round 1
// baseline (88.573 us; speedup 1.0000x reference)
//
#include <hip/hip_runtime.h>

// Problem geometry: input/target are (1, 3, 96, 256, 256) float32, contiguous.
// Each channel is a contiguous block of 96*256*256 = 6,291,456 floats.
#define NCH 3
#define PER_CH 6291456
#define PER_CH4 (PER_CH / 4)   // 1,572,864 float4 per channel
#define EPS 1e-6f

// acc layout in d_ws: acc[ch*3 + 0] = sum(x*t), +1 = sum(x*x), +2 = sum(t*t)
__global__ void __launch_bounds__(256)
dice_reduce_kernel(const float4* __restrict__ x, const float4* __restrict__ t,
                   float* __restrict__ acc) {
    const int ch = blockIdx.y;
    const long long base = (long long)ch * PER_CH4;

    float sxt = 0.f, sxx = 0.f, stt = 0.f;
    const int stride = gridDim.x * blockDim.x;
    for (int i = blockIdx.x * blockDim.x + threadIdx.x; i < PER_CH4; i += stride) {
        float4 xv = x[base + i];
        float4 tv = t[base + i];
        sxt += xv.x * tv.x + xv.y * tv.y + xv.z * tv.z + xv.w * tv.w;
        sxx += xv.x * xv.x + xv.y * xv.y + xv.z * xv.z + xv.w * xv.w;
        stt += tv.x * tv.x + tv.y * tv.y + tv.z * tv.z + tv.w * tv.w;
    }

    // Wave-64 reduction
    for (int off = 32; off > 0; off >>= 1) {
        sxt += __shfl_down(sxt, off, 64);
        sxx += __shfl_down(sxx, off, 64);
        stt += __shfl_down(stt, off, 64);
    }

    // Cross-wave reduction via LDS (256 threads = 4 waves)
    __shared__ float lds[3][4];
    const int lane = threadIdx.x & 63;
    const int wave = threadIdx.x >> 6;
    if (lane == 0) {
        lds[0][wave] = sxt;
        lds[1][wave] = sxx;
        lds[2][wave] = stt;
    }
    __syncthreads();
    if (threadIdx.x == 0) {
        float bxt = lds[0][0] + lds[0][1] + lds[0][2] + lds[0][3];
        float bxx = lds[1][0] + lds[1][1] + lds[1][2] + lds[1][3];
        float btt = lds[2][0] + lds[2][1] + lds[2][2] + lds[2][3];
        atomicAdd(&acc[ch * 3 + 0], bxt);
        atomicAdd(&acc[ch * 3 + 1], bxx);
        atomicAdd(&acc[ch * 3 + 2], btt);
    }
}

__global__ void dice_finalize_kernel(const float* __restrict__ acc,
                                     float* __restrict__ out) {
    if (threadIdx.x == 0 && blockIdx.x == 0) {
        float loss = 0.f;
        for (int c = 0; c < NCH; ++c) {
            float num = acc[c * 3 + 0];
            float den = acc[c * 3 + 1] + acc[c * 3 + 2];
            loss += -2.f * (num / fmaxf(den, EPS));
        }
        out[0] = loss;
    }
}

extern "C" void kernel_launch(void* const* d_in, const int* in_sizes, int n_in,
                              void* d_out, int out_size, void* d_ws, size_t ws_size,
                              hipStream_t stream) {
    const float4* x = (const float4*)d_in[0];
    const float4* t = (const float4*)d_in[1];
    float* acc = (float*)d_ws;
    float* out = (float*)d_out;

    // Workspace is poisoned (0xAA) and never re-poisoned between replays:
    // zero the 9 accumulators every call.
    hipMemsetAsync(acc, 0, NCH * 3 * sizeof(float), stream);

    dim3 grid(512, NCH);
    dice_reduce_kernel<<<grid, 256, 0, stream>>>(x, t, acc);
    dice_finalize_kernel<<<1, 64, 0, stream>>>(acc, out);
}